// Round 3
// baseline (71.830 us; speedup 1.0000x reference)
//
#include <hip/hip_runtime.h>
#include <hip/hip_bf16.h>

// out = conv13(in) @ M^T = conv13(in @ M^T),  M = Wout @ Win  (all row-major [f][e])
// g(d) = N(0,1) pdf; |d|<=6 truncation error ~1e-8.
// Kernel 1: gemm_m  -> M bf16 in ws.
// Kernel 2: fused   -> per block: Y = in @ M^T for 128 rows (112 out + 8 halo each side),
//                      Y -> LDS bf16, 13-tap conv along rows, fp32 out. No U intermediate.

typedef unsigned short u16;
typedef unsigned int u32;
typedef unsigned long long u64;
typedef __attribute__((ext_vector_type(8))) short bf16x8;
typedef __attribute__((ext_vector_type(8))) unsigned short u16x8;
typedef __attribute__((ext_vector_type(4))) float f32x4;
typedef __attribute__((ext_vector_type(2))) u32 u32x2;

typedef __attribute__((address_space(1))) const void* as1_cvp;
typedef __attribute__((address_space(3))) void* as3_vp;

#define EDIM 512
#define SEQ  4096
#define NROW 16384   // B*S
#define ROWS_OUT 112 // out rows per block (128 computed - 2*8 halo)
#define MBLK ((NROW + ROWS_OUT - 1) / ROWS_OUT)  // 147

__device__ __forceinline__ float b2f(u16 x) {
  union { u32 u; float f; } c; c.u = ((u32)x) << 16; return c.f;
}
__device__ __forceinline__ u16 f2b(float x) {
  union { float f; u32 u; } c; c.f = x;
  return (u16)((c.u + 0x7fffu + ((c.u >> 16) & 1u)) >> 16);  // RNE
}
__device__ __forceinline__ u32 cvtpk(float lo, float hi) {  // 2xf32 -> 2xbf16 (RNE)
  u32 r;
  asm("v_cvt_pk_bf16_f32 %0, %1, %2" : "=v"(r) : "v"(lo), "v"(hi));
  return r;
}
__device__ __forceinline__ void async_cp16(const void* g, void* l) {
  __builtin_amdgcn_global_load_lds((as1_cvp)(u64)g, (as3_vp)(u32)(u64)l, 16, 0, 0);
}

// ---------------------------------------------------------------------------
// Kernel 1: M[f,e] = sum_c Wout[f,c] * Win[c,e]  (512^3), fp32 in, bf16 out.
// ---------------------------------------------------------------------------
__global__ __launch_bounds__(256) void gemm_m(const float* __restrict__ Wout,
                                              const float* __restrict__ Win,
                                              u16* __restrict__ Mm) {
  __shared__ u16 la[64 * 32];
  __shared__ u16 lbt[64 * 32];
  int t = threadIdx.x;
  int w = t >> 6, l = t & 63, lr = l & 15, lk = l >> 4;
  int f0 = (int)(blockIdx.x >> 3) * 64, e0 = (int)(blockIdx.x & 7) * 64;
  f32x4 acc[4] = {};
  for (int kt = 0; kt < 16; ++kt) {
    int k0 = kt * 32;
    __syncthreads();
    {
      const float* src = Wout + (u64)(f0 + (t >> 2)) * EDIM + k0 + (t & 3) * 8;
      u16x8 o;
#pragma unroll
      for (int j = 0; j < 8; ++j) o[j] = f2b(src[j]);
      *(u16x8*)(la + (t >> 2) * 32 + (t & 3) * 8) = o;
    }
    {
      const float* src = Win + (u64)(k0 + (t >> 3)) * EDIM + e0 + (t & 7) * 8;
#pragma unroll
      for (int j = 0; j < 8; ++j) lbt[((t & 7) * 8 + j) * 32 + (t >> 3)] = f2b(src[j]);
    }
    __syncthreads();
    bf16x8 a = *(const bf16x8*)(la + (w * 16 + lr) * 32 + lk * 8);
#pragma unroll
    for (int ni = 0; ni < 4; ++ni) {
      bf16x8 b = *(const bf16x8*)(lbt + (ni * 16 + lr) * 32 + lk * 8);
      acc[ni] = __builtin_amdgcn_mfma_f32_16x16x32_bf16(a, b, acc[ni], 0, 0, 0);
    }
  }
#pragma unroll
  for (int ni = 0; ni < 4; ++ni)
#pragma unroll
    for (int r = 0; r < 4; ++r)
      Mm[(u64)(f0 + w * 16 + lk * 4 + r) * EDIM + e0 + ni * 16 + lr] = f2b(acc[ni][r]);
}

// ---------------------------------------------------------------------------
// Kernel 2: fused GEMM + conv epilogue.
// Grid: 147 m-blocks x 4 n-blocks. Block: 256 thr (4 waves, 2x2), computes
// Y[128 x 128] = in[m0c..m0c+128) @ M[n0..n0+128)^T with BK=64, 8 K-steps.
// A: fp32 reg-stage + cvt_pk -> LDS bf16 (next tile prefetched under MFMA).
// B: global_load_lds width-16 (bf16 M).
// Epilogue: acc -> LDS Y bf16 [128][136], 13-tap conv, fp32 out rows m0c+8..+119.
// ---------------------------------------------------------------------------
__global__ __launch_bounds__(256) void fused_gc(const float* __restrict__ in,
                                                const u16* __restrict__ Mm,
                                                float* __restrict__ out) {
  __shared__ u16 lds[17408];  // max(A 8192 + B 8192, Y 128*136=17408) u16 = 34 KB
  u16* la = lds;
  u16* lb = lds + 8192;
  int t = threadIdx.x;
  int l = t & 63, lr = l & 15, lk = l >> 4;
  int w = t >> 6, wr = w >> 1, wc = w & 1;
  int ib = (int)blockIdx.x >> 2;
  int n0 = ((int)blockIdx.x & 3) << 7;
  int m0c = ib * ROWS_OUT - 8;  // first computed (halo) row, may be <0 or run past end

  // per-thread A source row offsets (8 row-groups of 16), clamped to valid rows
  u32 rowoff[8];
#pragma unroll
  for (int j = 0; j < 8; ++j) {
    int rg = m0c + j * 16 + (t >> 4);
    rg = rg < 0 ? 0 : (rg > NROW - 1 ? NROW - 1 : rg);
    rowoff[j] = (u32)rg * EDIM + (t & 15) * 4;
  }
  const u16* gB = Mm + (u64)(n0 + (t >> 3)) * EDIM + (t & 7) * 8;
  u16* sB = lb + t * 8;

  f32x4 acc[4][4] = {};
  f32x4 ar[8];
#pragma unroll
  for (int j = 0; j < 8; ++j) ar[j] = *(const f32x4*)(in + rowoff[j]);  // kt=0

  for (int kt = 0; kt < 8; ++kt) {
    int k0 = kt * 64;
#pragma unroll
    for (int i = 0; i < 4; ++i)
      async_cp16(gB + (u64)i * 32 * EDIM + k0, sB + i * 2048);
    // A regs -> bf16 -> LDS [row][64]
#pragma unroll
    for (int j = 0; j < 8; ++j) {
      u32x2 p;
      p[0] = cvtpk(ar[j][0], ar[j][1]);
      p[1] = cvtpk(ar[j][2], ar[j][3]);
      *(u32x2*)(la + (j * 16 + (t >> 4)) * 64 + (t & 15) * 4) = p;
    }
    __syncthreads();  // drains vmcnt (B) + lgkm (A writes)
    if (kt < 7) {     // prefetch next A tile under the MFMA phase
#pragma unroll
      for (int j = 0; j < 8; ++j)
        ar[j] = *(const f32x4*)(in + rowoff[j] + k0 + 64);
    }
#pragma unroll
    for (int kk = 0; kk < 64; kk += 32) {
      bf16x8 af[4], bfr[4];
#pragma unroll
      for (int mi = 0; mi < 4; ++mi)
        af[mi] = *(const bf16x8*)(la + (wr * 64 + mi * 16 + lr) * 64 + kk + lk * 8);
#pragma unroll
      for (int ni = 0; ni < 4; ++ni)
        bfr[ni] = *(const bf16x8*)(lb + (wc * 64 + ni * 16 + lr) * 64 + kk + lk * 8);
#pragma unroll
      for (int mi = 0; mi < 4; ++mi)
#pragma unroll
        for (int ni = 0; ni < 4; ++ni)
          acc[mi][ni] = __builtin_amdgcn_mfma_f32_16x16x32_bf16(af[mi], bfr[ni],
                                                                acc[mi][ni], 0, 0, 0);
    }
    __syncthreads();
  }

  // ---- epilogue: Y -> LDS bf16 [128][136] (pad 8 -> 272B stride, bank-rotated)
  u16* Y = lds;
#pragma unroll
  for (int mi = 0; mi < 4; ++mi)
#pragma unroll
    for (int ni = 0; ni < 4; ++ni)
#pragma unroll
      for (int r = 0; r < 4; ++r)
        Y[(wr * 64 + mi * 16 + lk * 4 + r) * 136 + wc * 64 + ni * 16 + lr] =
            f2b(acc[mi][ni][r]);
  __syncthreads();

  const float G[7] = {0.39894228040143270f, 0.24197072451914337f,
                      0.053990966513188063f, 0.0044318484119380075f,
                      1.3383022576488537e-4f, 1.4867195147342977e-6f,
                      6.0758828498232861e-9f};
  // 112 out rows x 16 col-octets = 1792 slots = 7 per thread
#pragma unroll
  for (int j = 0; j < 7; ++j) {
    int slot = j * 256 + t;
    int rl = 8 + (slot >> 4);   // local computed-row index, 8..119
    int oc = slot & 15;
    int rg = m0c + rl;          // global out row (>=0 always; may be >= NROW at tail)
    if (rg < NROW) {
      int bat = rg >> 12;       // 4096 rows per batch
      float a[8] = {0.f, 0.f, 0.f, 0.f, 0.f, 0.f, 0.f, 0.f};
#pragma unroll
      for (int d = -6; d <= 6; ++d) {
        int rt = rg + d;
        float g = ((rt >> 12) == bat) ? G[d < 0 ? -d : d] : 0.0f;  // arith shift: rt<0 -> -1
        u16x8 y = *(const u16x8*)(Y + (rl + d) * 136 + oc * 8);
#pragma unroll
        for (int q = 0; q < 8; ++q) a[q] += g * b2f(y[q]);
      }
      f32x4 o0, o1;
#pragma unroll
      for (int q = 0; q < 4; ++q) { o0[q] = a[q]; o1[q] = a[4 + q]; }
      float* dst = out + (u64)rg * EDIM + n0 + oc * 8;
      *(f32x4*)dst = o0;
      *(f32x4*)(dst + 4) = o1;
    }
  }
}

extern "C" void kernel_launch(void* const* d_in, const int* in_sizes, int n_in,
                              void* d_out, int out_size, void* d_ws, size_t ws_size,
                              hipStream_t stream) {
  const float* in   = (const float*)d_in[0];  // [4,4096,512] f32
  const float* Win  = (const float*)d_in[1];  // [512,512] f32
  const float* Wout = (const float*)d_in[2];  // [512,512] f32
  float* outp = (float*)d_out;                // [4,4096,512] f32

  u16* Mm = (u16*)d_ws;  // 512*512 bf16

  hipLaunchKernelGGL(gemm_m,   dim3(64), dim3(256), 0, stream, Wout, Win, Mm);
  hipLaunchKernelGGL(fused_gc, dim3(MBLK * 4), dim3(256), 0, stream, in, Mm, outp);
}

// Round 4
// 58.736 us; speedup vs baseline: 1.2229x; 1.2229x over previous
//
#include <hip/hip_runtime.h>
#include <hip/hip_bf16.h>

// out = conv13(in @ M^T),  M = Wout @ Win   (conv commutes with the channel GEMMs)
// g(d) = N(0,1) pdf; |d|<=6 truncation error ~1e-8.
// R4: 2-phase double-buffered pipeline (T3-min), T2 XOR swizzle both-sides,
//     bijective XCD swizzle (m204) so same-m n-blocks share an XCD L2.

typedef unsigned short u16;
typedef unsigned int u32;
typedef unsigned long long u64;
typedef __attribute__((ext_vector_type(8))) short bf16x8;
typedef __attribute__((ext_vector_type(8))) unsigned short u16x8;
typedef __attribute__((ext_vector_type(4))) float f32x4;
typedef __attribute__((ext_vector_type(2))) u32 u32x2;

typedef __attribute__((address_space(1))) const void* as1_cvp;
typedef __attribute__((address_space(3))) void* as3_vp;

#define EDIM 512
#define SEQ  4096
#define NROW 16384
#define ROWS_OUT 112
#define MBLK ((NROW + ROWS_OUT - 1) / ROWS_OUT)  // 147
#define NWG (MBLK * 4)                            // 588

__device__ __forceinline__ float b2f(u16 x) {
  union { u32 u; float f; } c; c.u = ((u32)x) << 16; return c.f;
}
__device__ __forceinline__ u16 f2b(float x) {
  union { float f; u32 u; } c; c.f = x;
  return (u16)((c.u + 0x7fffu + ((c.u >> 16) & 1u)) >> 16);  // RNE
}
__device__ __forceinline__ u32 cvtpk(float lo, float hi) {
  u32 r;
  asm("v_cvt_pk_bf16_f32 %0, %1, %2" : "=v"(r) : "v"(lo), "v"(hi));
  return r;
}
__device__ __forceinline__ void async_cp16(const void* g, void* l) {
  __builtin_amdgcn_global_load_lds((as1_cvp)(u64)g, (as3_vp)(u32)(u64)l, 16, 0, 0);
}

// ---------------------------------------------------------------------------
// Kernel 1: M[f,e] = sum_c Wout[f,c] * Win[c,e]  (512^3), fp32 in, bf16 out.
// ---------------------------------------------------------------------------
__global__ __launch_bounds__(256) void gemm_m(const float* __restrict__ Wout,
                                              const float* __restrict__ Win,
                                              u16* __restrict__ Mm) {
  __shared__ u16 la[64 * 32];
  __shared__ u16 lbt[64 * 32];
  int t = threadIdx.x;
  int w = t >> 6, l = t & 63, lr = l & 15, lk = l >> 4;
  int f0 = (int)(blockIdx.x >> 3) * 64, e0 = (int)(blockIdx.x & 7) * 64;
  f32x4 acc[4] = {};
  for (int kt = 0; kt < 16; ++kt) {
    int k0 = kt * 32;
    __syncthreads();
    {
      const float* src = Wout + (u64)(f0 + (t >> 2)) * EDIM + k0 + (t & 3) * 8;
      u16x8 o;
#pragma unroll
      for (int j = 0; j < 8; ++j) o[j] = f2b(src[j]);
      *(u16x8*)(la + (t >> 2) * 32 + (t & 3) * 8) = o;
    }
    {
      const float* src = Win + (u64)(k0 + (t >> 3)) * EDIM + e0 + (t & 7) * 8;
#pragma unroll
      for (int j = 0; j < 8; ++j) lbt[((t & 7) * 8 + j) * 32 + (t >> 3)] = f2b(src[j]);
    }
    __syncthreads();
    bf16x8 a = *(const bf16x8*)(la + (w * 16 + lr) * 32 + lk * 8);
#pragma unroll
    for (int ni = 0; ni < 4; ++ni) {
      bf16x8 b = *(const bf16x8*)(lbt + (ni * 16 + lr) * 32 + lk * 8);
      acc[ni] = __builtin_amdgcn_mfma_f32_16x16x32_bf16(a, b, acc[ni], 0, 0, 0);
    }
  }
#pragma unroll
  for (int ni = 0; ni < 4; ++ni)
#pragma unroll
    for (int r = 0; r < 4; ++r)
      Mm[(u64)(f0 + w * 16 + lk * 4 + r) * EDIM + e0 + ni * 16 + lr] = f2b(acc[ni][r]);
}

// ---------------------------------------------------------------------------
// Kernel 2: fused GEMM + conv epilogue, 2-phase double-buffered.
// LDS: A0|A1|B0|B1, each [128][64] bf16 = 16KB (64KB total). Y reuses first 34KB.
// T2 swizzle: u16 idx ^= (row&7)<<3 on A write + A/B reads; B via pre-swizzled
// global source (global_load_lds dest stays linear, rule #21).
// ---------------------------------------------------------------------------
__global__ __launch_bounds__(256) void fused_gc(const float* __restrict__ in,
                                                const u16* __restrict__ Mm,
                                                float* __restrict__ out) {
  __shared__ u16 lds[32768];  // 64 KB
  int t = threadIdx.x;
  int l = t & 63, lr = l & 15, lk = l >> 4;
  int w = t >> 6, wr = w >> 1, wc = w & 1;

  // bijective XCD swizzle (m204): same-m n-blocks land on one XCD
  int b = (int)blockIdx.x;
  int q = NWG >> 3, r = NWG & 7;           // 73, 4
  int xcd = b & 7, off = b >> 3;
  int wg = (xcd < r ? xcd * (q + 1) : r * (q + 1) + (xcd - r) * q) + off;
  int ib = wg >> 2;
  int n0 = (wg & 3) << 7;
  int m0c = ib * ROWS_OUT - 8;

  // A source rows (clamped); lane covers 4 fp32 at col (t&15)*4 of 8 row-groups
  u32 rowoff[8];
#pragma unroll
  for (int j = 0; j < 8; ++j) {
    int rg = m0c + j * 16 + (t >> 4);
    rg = rg < 0 ? 0 : (rg > NROW - 1 ? NROW - 1 : rg);
    rowoff[j] = (u32)rg * EDIM + (t & 15) * 4;
  }
  // B global source, col-octet pre-swizzled: octet (t&7) ^ ((t>>3)&7)
  const u16* gB = Mm + (u64)(n0 + (t >> 3)) * EDIM + (((t & 7) ^ ((t >> 3) & 7)) * 8);

  // A LDS write idx (u16), swizzled
  int aw_idx[8];
#pragma unroll
  for (int j = 0; j < 8; ++j) {
    int row = j * 16 + (t >> 4);
    aw_idx[j] = (row * 64 + (t & 15) * 4) ^ ((row & 7) << 3);
  }
  // fragment read idx (u16), swizzled; +kk per step
  int ard[4], brd[4];
#pragma unroll
  for (int mi = 0; mi < 4; ++mi) {
    int row = wr * 64 + mi * 16 + lr;
    ard[mi] = (row * 64 + lk * 8) ^ ((row & 7) << 3);
  }
#pragma unroll
  for (int ni = 0; ni < 4; ++ni) {
    int row = wc * 64 + ni * 16 + lr;
    brd[ni] = (row * 64 + lk * 8) ^ ((row & 7) << 3);
  }

  f32x4 acc[4][4] = {};
  f32x4 ar[8];

  // ---- prologue: stage tile 0
#pragma unroll
  for (int j = 0; j < 8; ++j) ar[j] = *(const f32x4*)(in + rowoff[j]);
#pragma unroll
  for (int i = 0; i < 4; ++i)
    async_cp16(gB, lds + 16384 + t * 8 + i * 2048), gB += 32 * EDIM;
  gB -= 128 * EDIM;
#pragma unroll
  for (int j = 0; j < 8; ++j) {
    u32x2 p;
    p[0] = cvtpk(ar[j][0], ar[j][1]);
    p[1] = cvtpk(ar[j][2], ar[j][3]);
    *(u32x2*)(lds + aw_idx[j]) = p;
  }
  __syncthreads();

  int cur = 0;
  for (int kt = 0; kt < 8; ++kt) {
    int k1 = kt * 64 + 64;
    int nxt = cur ^ 1;
    if (kt < 7) {  // issue next-tile loads BEFORE compute (latency hides under MFMA)
#pragma unroll
      for (int j = 0; j < 8; ++j) ar[j] = *(const f32x4*)(in + rowoff[j] + k1);
#pragma unroll
      for (int i = 0; i < 4; ++i)
        async_cp16(gB + k1 + (u64)i * 32 * EDIM, lds + 16384 + nxt * 8192 + t * 8 + i * 2048);
    }
    // compute tile kt from buffers [cur]
    int abase = cur * 8192, bbase = 16384 + cur * 8192;
#pragma unroll
    for (int kk = 0; kk < 64; kk += 32) {
      bf16x8 af[4], bfr[4];
#pragma unroll
      for (int mi = 0; mi < 4; ++mi)
        af[mi] = *(const bf16x8*)(lds + abase + (ard[mi] ^ kk));  // kk in swz-free bits? no:
      // kk=32 flips u16 bit5 which swz may also flip -> use add on pre-XOR form:
#pragma unroll
      for (int ni = 0; ni < 4; ++ni)
        bfr[ni] = *(const bf16x8*)(lds + bbase + (brd[ni] ^ kk));
#pragma unroll
      for (int mi = 0; mi < 4; ++mi)
#pragma unroll
        for (int ni = 0; ni < 4; ++ni)
          acc[mi][ni] = __builtin_amdgcn_mfma_f32_16x16x32_bf16(af[mi], bfr[ni],
                                                                acc[mi][ni], 0, 0, 0);
    }
    if (kt < 7) {  // A regs -> bf16 -> LDS buf[nxt]
#pragma unroll
      for (int j = 0; j < 8; ++j) {
        u32x2 p;
        p[0] = cvtpk(ar[j][0], ar[j][1]);
        p[1] = cvtpk(ar[j][2], ar[j][3]);
        *(u32x2*)(lds + nxt * 8192 + aw_idx[j]) = p;
      }
    }
    __syncthreads();
    cur = nxt;
  }
  // NOTE on kk XOR: idx = (row*64 + base8) ^ ((row&7)<<3); adding kk (32) only
  // touches u16 bit 5; swz touches bits 3..5. (x ^ swz) ^ kk == (x + kk) ^ swz
  // iff bit5 of x is 0 pre-swz (base8 = lk*8 <= 24, so row*64+lk*8 has bit5 = 0
  // only when lk<4: lk*8 in {0,8,16,24} -> bit5=0 yes) and no carry: adding 32
  // to a value with bit5=0 sets bit5, no carry. XOR with swz(bits3-5) commutes
  // with setting bit5 only if swz bit5 unchanged — XOR then add-32 could carry
  // if swz set bit5. Using ^kk on the post-swz idx flips bit5 directly, which
  // equals (row*64 + lk*8 + kk) ^ swz when bit5 of (row*64+lk*8) is 0. OK.

  // ---- epilogue: Y[128][136] bf16 in LDS (padded), 13-tap conv, fp32 out
  u16* Y = lds;
#pragma unroll
  for (int mi = 0; mi < 4; ++mi)
#pragma unroll
    for (int ni = 0; ni < 4; ++ni)
#pragma unroll
      for (int rr = 0; rr < 4; ++rr)
        Y[(wr * 64 + mi * 16 + lk * 4 + rr) * 136 + wc * 64 + ni * 16 + lr] =
            f2b(acc[mi][ni][rr]);
  __syncthreads();

  const float G[7] = {0.39894228040143270f, 0.24197072451914337f,
                      0.053990966513188063f, 0.0044318484119380075f,
                      1.3383022576488537e-4f, 1.4867195147342977e-6f,
                      6.0758828498232861e-9f};
#pragma unroll
  for (int j = 0; j < 7; ++j) {
    int slot = j * 256 + t;
    int rl = 8 + (slot >> 4);
    int oc = slot & 15;
    int rg = m0c + rl;
    if (rg < NROW) {
      int bat = rg >> 12;
      float a[8] = {0.f, 0.f, 0.f, 0.f, 0.f, 0.f, 0.f, 0.f};
#pragma unroll
      for (int d = -6; d <= 6; ++d) {
        int rt = rg + d;
        float g = ((rt >> 12) == bat) ? G[d < 0 ? -d : d] : 0.0f;
        u16x8 y = *(const u16x8*)(Y + (rl + d) * 136 + oc * 8);
#pragma unroll
        for (int qq = 0; qq < 8; ++qq) a[qq] += g * b2f(y[qq]);
      }
      f32x4 o0, o1;
#pragma unroll
      for (int qq = 0; qq < 4; ++qq) { o0[qq] = a[qq]; o1[qq] = a[4 + qq]; }
      float* dst = out + (u64)rg * EDIM + n0 + oc * 8;
      *(f32x4*)dst = o0;
      *(f32x4*)(dst + 4) = o1;
    }
  }
}

extern "C" void kernel_launch(void* const* d_in, const int* in_sizes, int n_in,
                              void* d_out, int out_size, void* d_ws, size_t ws_size,
                              hipStream_t stream) {
  const float* in   = (const float*)d_in[0];
  const float* Win  = (const float*)d_in[1];
  const float* Wout = (const float*)d_in[2];
  float* outp = (float*)d_out;

  u16* Mm = (u16*)d_ws;

  hipLaunchKernelGGL(gemm_m,   dim3(64), dim3(256), 0, stream, Wout, Win, Mm);
  hipLaunchKernelGGL(fused_gc, dim3(NWG), dim3(256), 0, stream, in, Mm, outp);
}